// Round 11
// baseline (34.280 us; speedup 1.0000x reference)
//
#include <hip/hip_runtime.h>

#define N_DOCS 500000
#define N_WORDS 100000
#define EMB 128
#define BATCH 16384
#define CTX 8
#define K 6
#define TW 64
#define LSTRIDE 67  // f32 LDS row stride: write-phase <=4-way, read-phase <=2-way banks
#define NTB ((N_WORDS + TW - 1) / TW)  // 1563

__device__ __forceinline__ unsigned f2bf(float f) {
    unsigned u = __float_as_uint(f);
    unsigned r = u + 0x7fffu + ((u >> 16) & 1u);  // round-to-nearest-even
    return r >> 16;
}
#define BF2F(h) __uint_as_float(((unsigned)(h)) << 16)

// ---------------------------------------------------------------------------
// Transpose Wp [EMB, N_WORDS] f32 -> WpT [N_WORDS, EMB] bf16 (round-9, ~BW floor).
// ---------------------------------------------------------------------------
__global__ __launch_bounds__(256) void transpose_bf16(const float* __restrict__ Wp,
                                                      unsigned short* __restrict__ WpT) {
    __shared__ float tile[EMB * LSTRIDE];
    const int t = threadIdx.x;
    const int w0 = blockIdx.x * TW;

    {
        const int fq = t & 15, e0 = t >> 4;
        const int col = w0 + 4 * fq;
        if (col + 3 < N_WORDS) {
#pragma unroll
            for (int j = 0; j < 8; ++j) {
                const int e = e0 + 16 * j;
                const float4 v = *(const float4*)(Wp + (size_t)e * N_WORDS + col);
                float* d = &tile[e * LSTRIDE + 4 * fq];
                d[0] = v.x; d[1] = v.y; d[2] = v.z; d[3] = v.w;
            }
        }
    }
    __syncthreads();

#pragma unroll
    for (int r = 0; r < 4; ++r) {
        const int wl = 16 * r + (t >> 4);
        const int w = w0 + wl;
        if (w < N_WORDS) {
            const int db = 8 * (t & 15);
            float c[8];
#pragma unroll
            for (int j = 0; j < 8; ++j) c[j] = tile[(db + j) * LSTRIDE + wl];
            uint4 o;
            o.x = f2bf(c[0]) | (f2bf(c[1]) << 16);
            o.y = f2bf(c[2]) | (f2bf(c[3]) << 16);
            o.z = f2bf(c[4]) | (f2bf(c[5]) << 16);
            o.w = f2bf(c[6]) | (f2bf(c[7]) << 16);
            *(uint4*)(WpT + (size_t)w * EMB + db) = o;
        }
    }
}

// ---------------------------------------------------------------------------
// Fused v3: HALF-WAVE (32 lanes x 4 dims) per b. One float4/lane -> every
// 512B row-gather is a single wave-instruction. 8 b's per 256-thread block
// -> 2048 blocks, 32 waves/CU. Low VGPR; __launch_bounds__(256, 8).
// ---------------------------------------------------------------------------
__global__ __launch_bounds__(256, 8) void nce_fused8(const float* __restrict__ D,
                                                     const float* __restrict__ W,
                                                     const unsigned short* __restrict__ WpT,
                                                     const int* __restrict__ ctx_ids,
                                                     const int* __restrict__ doc_ids,
                                                     const int* __restrict__ tn_ids,
                                                     float* __restrict__ out) {
    const int t = threadIdx.x;
    const int lane = t & 63;
    const int li = lane & 31;  // lane within half
    const int b = blockIdx.x * 8 + (t >> 6) * 2 + (lane >> 5);

    // ids: uniform within each half-wave -> broadcast loads
    const int doc = doc_ids[b];
    int cids[CTX];
#pragma unroll
    for (int c = 0; c < CTX; ++c) cids[c] = ctx_ids[b * CTX + c];
    int ids[K];
#pragma unroll
    for (int k = 0; k < K; ++k) ids[k] = tn_ids[b * K + k];

    // x phase: dims li*4 .. li*4+3 in one float4
    float4 a = *(const float4*)(D + (size_t)doc * EMB + li * 4);
#pragma unroll
    for (int c = 0; c < CTX; ++c) {
        const float4 w = *(const float4*)(W + (size_t)cids[c] * EMB + li * 4);
        a.x += w.x; a.y += w.y; a.z += w.z; a.w += w.w;
    }

    // dot phase: prefetch all 6 WpT fragments (uint2 = 4 bf16), then reduce
    uint2 wf[K];
#pragma unroll
    for (int k = 0; k < K; ++k)
        wf[k] = *(const uint2*)(WpT + (size_t)ids[k] * EMB + li * 4);

#pragma unroll
    for (int k = 0; k < K; ++k) {
        const uint2 u = wf[k];
        float s = BF2F(u.x & 0xffff) * a.x + BF2F(u.x >> 16) * a.y +
                  BF2F(u.y & 0xffff) * a.z + BF2F(u.y >> 16) * a.w;
        s += __shfl_xor(s, 16, 64);
        s += __shfl_xor(s, 8, 64);
        s += __shfl_xor(s, 4, 64);
        s += __shfl_xor(s, 2, 64);
        s += __shfl_xor(s, 1, 64);
        if (li == 0) out[b * K + k] = s;
    }
}

// ---------------------------------------------------------------------------
// Fallback (no workspace): direct strided column gather.
// ---------------------------------------------------------------------------
__global__ __launch_bounds__(256) void nce_direct(
    const float* __restrict__ D, const float* __restrict__ W,
    const float* __restrict__ Wp, const int* __restrict__ ctx_ids,
    const int* __restrict__ doc_ids, const int* __restrict__ tn_ids,
    float* __restrict__ out) {
    const int wave = threadIdx.x >> 6, lane = threadIdx.x & 63;
    const int b = blockIdx.x * 4 + wave;
    if (b >= BATCH) return;
    float2 xx = ((const float2*)(D + (size_t)doc_ids[b] * EMB))[lane];
#pragma unroll
    for (int c = 0; c < CTX; ++c) {
        const float2 w2 = ((const float2*)(W + (size_t)ctx_ids[b * CTX + c] * EMB))[lane];
        xx.x += w2.x;
        xx.y += w2.y;
    }
#pragma unroll
    for (int k = 0; k < K; ++k) {
        const int id = tn_ids[b * K + k];
        float s = xx.x * Wp[(size_t)(2 * lane) * N_WORDS + id] +
                  xx.y * Wp[(size_t)(2 * lane + 1) * N_WORDS + id];
#pragma unroll
        for (int off = 32; off > 0; off >>= 1) s += __shfl_down(s, off, 64);
        if (lane == 0) out[b * K + k] = s;
    }
}

extern "C" void kernel_launch(void* const* d_in, const int* in_sizes, int n_in,
                              void* d_out, int out_size, void* d_ws, size_t ws_size,
                              hipStream_t stream) {
    const float* D  = (const float*)d_in[0];
    const float* W  = (const float*)d_in[1];
    const float* Wp = (const float*)d_in[2];
    const int* ctx  = (const int*)d_in[3];
    const int* doc  = (const int*)d_in[4];
    const int* tn   = (const int*)d_in[5];
    float* out = (float*)d_out;

    const size_t need = (size_t)N_WORDS * EMB * sizeof(unsigned short);  // 25.6 MB
    if (ws_size >= need) {
        unsigned short* WpT = (unsigned short*)d_ws;
        transpose_bf16<<<NTB, 256, 0, stream>>>(Wp, WpT);
        nce_fused8<<<BATCH / 8, 256, 0, stream>>>(D, W, WpT, ctx, doc, tn, out);
    } else {
        nce_direct<<<BATCH / 4, 256, 0, stream>>>(D, W, Wp, ctx, doc, tn, out);
    }
}